// Round 2
// baseline (480.499 us; speedup 1.0000x reference)
//
#include <hip/hip_runtime.h>
#include <math.h>

// Reverse cummax along axis 1 of a [B=16, H=128, W=128, C=256] fp32 tensor.
// out[b,h,w,c] = max_{h'>=h} in[b,h',w,c].
//
// Two-pass chunked suffix scan (max is associative):
//   K1: per (b,chunk,w,c4) thread computes max over its 16-h chunk -> ws.
//   K2: seed = suffix-max of later chunk totals, then walk own chunk
//       backwards emitting the running max.
// 8x more threads than the one-pass version, 16 independent loads per
// thread, bounded 16-step streams (no long-range wave drift).

#define B   16
#define H   128
#define W   128
#define C4  64            // C/4 = 256/4
#define NCH 8             // number of h-chunks
#define CH  16            // H / NCH
#define HS  (W * C4)      // float4 elements per h step (8192)

// Native clang vector type: __builtin_nontemporal_store rejects the
// HIP_vector_type class wrapper, but accepts this.
typedef float vfloat4 __attribute__((ext_vector_type(4)));

__device__ __forceinline__ float4 fmax4(float4 a, float4 b) {
    a.x = fmaxf(a.x, b.x);
    a.y = fmaxf(a.y, b.y);
    a.z = fmaxf(a.z, b.z);
    a.w = fmaxf(a.w, b.w);
    return a;
}

__device__ __forceinline__ void store_nt(float4* p, float4 v) {
    vfloat4 nv;
    nv.x = v.x; nv.y = v.y; nv.z = v.z; nv.w = v.w;
    __builtin_nontemporal_store(nv, (vfloat4*)p);
}

// Kernel 1: chunk totals. ws[((b*NCH+ch)*W+w)*C4+c4] = max over chunk ch.
__global__ void __launch_bounds__(256) chunk_max_kernel(
    const float4* __restrict__ in, float4* __restrict__ ws) {
    int tid = blockIdx.x * 256 + threadIdx.x;   // 0 .. B*NCH*W*C4-1
    int c4 = tid & (C4 - 1);
    int w  = (tid >> 6) & (W - 1);
    int ch = (tid >> 13) & (NCH - 1);
    int b  = tid >> 16;

    int idx = ((b * H + ch * CH + (CH - 1)) * W + w) * C4 + c4;

    float4 m = in[idx];
#pragma unroll
    for (int i = 1; i < CH; ++i) {
        idx -= HS;
        m = fmax4(m, in[idx]);   // loads independent: deep MLP
    }
    ws[((b * NCH + ch) * W + w) * C4 + c4] = m;
}

// Kernel 2: final suffix scan within each chunk, seeded by later chunks.
__global__ void __launch_bounds__(256) suffix_scan_kernel(
    const float4* __restrict__ in, const float4* __restrict__ ws,
    float4* __restrict__ out) {
    int tid = blockIdx.x * 256 + threadIdx.x;
    int c4 = tid & (C4 - 1);
    int w  = (tid >> 6) & (W - 1);
    int ch = (tid >> 13) & (NCH - 1);   // wave-uniform (low 6 bits are c4)
    int b  = tid >> 16;

    // Seed: max over totals of all later chunks (ws is 16 MiB, L2/L3-hot).
    float4 m = make_float4(-INFINITY, -INFINITY, -INFINITY, -INFINITY);
    for (int j = ch + 1; j < NCH; ++j)
        m = fmax4(m, ws[((b * NCH + j) * W + w) * C4 + c4]);

    int idx = ((b * H + ch * CH + (CH - 1)) * W + w) * C4 + c4;
#pragma unroll
    for (int i = 0; i < CH; ++i) {
        float4 v = in[idx];              // loads independent
        m = fmax4(m, v);
        store_nt(&out[idx], m);          // out never re-read
        idx -= HS;
    }
}

// Fallback: original one-pass kernel (used only if workspace too small).
__global__ void __launch_bounds__(256) rev_cummax_kernel(
    const float4* __restrict__ in, float4* __restrict__ out) {
    int tid = blockIdx.x * blockDim.x + threadIdx.x;
    int c4 = tid & (C4 - 1);
    int w  = (tid >> 6) & (W - 1);
    int b  = tid >> 13;

    int idx = ((b * H + (H - 1)) * W + w) * C4 + c4;

    float4 m = in[idx];
    out[idx] = m;
    idx -= HS;

#pragma unroll 4
    for (int h = H - 2; h >= 0; --h) {
        float4 v = in[idx];
        m = fmax4(m, v);
        out[idx] = m;
        idx -= HS;
    }
}

extern "C" void kernel_launch(void* const* d_in, const int* in_sizes, int n_in,
                              void* d_out, int out_size, void* d_ws, size_t ws_size,
                              hipStream_t stream) {
    const float4* in = (const float4*)d_in[0];
    float4* out = (float4*)d_out;

    const size_t ws_needed = (size_t)B * NCH * W * C4 * sizeof(float4);  // 16 MiB
    if (d_ws != nullptr && ws_size >= ws_needed) {
        float4* ws = (float4*)d_ws;
        const int nthreads = B * NCH * W * C4;  // 1,048,576
        chunk_max_kernel<<<nthreads / 256, 256, 0, stream>>>(in, ws);
        suffix_scan_kernel<<<nthreads / 256, 256, 0, stream>>>(in, ws, out);
    } else {
        const int nthreads = B * W * C4;  // 131,072
        rev_cummax_kernel<<<nthreads / 256, 256, 0, stream>>>(in, out);
    }
}

// Round 3
// 465.494 us; speedup vs baseline: 1.0322x; 1.0322x over previous
//
#include <hip/hip_runtime.h>
#include <math.h>

// Reverse cummax along axis 1 of a [B=16, H=128, W=128, C=256] fp32 tensor.
// out[b,h,w,c] = max_{h'>=h} in[b,h',w,c].
//
// One-pass, minimal traffic (268 MB read + 268 MB write — provably minimal).
// One thread per (b,w,c4) column, walking h backwards in software-pipelined
// batches of 8: the NEXT batch's 8 independent loads are issued before the
// CURRENT batch's max+store chain, so loads are never queued behind the
// dependent stores in the vmcnt stream. 8 KB per wave in flight.
// Nontemporal dwordx4 stores: out is never re-read.

#define B   16
#define H   128
#define W   128
#define C4  64            // C/4
#define HS  (W * C4)      // float4 elements per h step (8192)
#define UN  8             // batch size (loads in flight per wave)
#define NB  (H / UN)      // 16 batches

typedef float vfloat4 __attribute__((ext_vector_type(4)));

__device__ __forceinline__ float4 fmax4(float4 a, float4 b) {
    a.x = fmaxf(a.x, b.x);
    a.y = fmaxf(a.y, b.y);
    a.z = fmaxf(a.z, b.z);
    a.w = fmaxf(a.w, b.w);
    return a;
}

__device__ __forceinline__ void store_nt(float4* p, float4 v) {
    vfloat4 nv;
    nv.x = v.x; nv.y = v.y; nv.z = v.z; nv.w = v.w;
    __builtin_nontemporal_store(nv, (vfloat4*)p);
}

__global__ void __launch_bounds__(256) rev_cummax_kernel(
    const float4* __restrict__ in, float4* __restrict__ out) {
    int tid = blockIdx.x * 256 + threadIdx.x;  // 0 .. B*W*C4-1
    int c4 = tid & (C4 - 1);
    int w  = (tid >> 6) & (W - 1);
    int b  = tid >> 13;

    const int base = (b * H * W + w) * C4 + c4;   // h = 0 element
    const float4* __restrict__ pin  = in  + base;
    float4*       __restrict__ pout = out + base;

    // Prologue: load top batch (h = H-UN .. H-1), all independent.
    int hbase = H - UN;
    float4 v[UN];
#pragma unroll
    for (int k = 0; k < UN; ++k) v[k] = pin[(hbase + k) * HS];

    float4 m = make_float4(-INFINITY, -INFINITY, -INFINITY, -INFINITY);

    for (int nb = 0; nb < NB; ++nb) {
        // Issue next batch's loads FIRST (independent of m-chain and stores).
        float4 nv[UN];
        const int nhbase = hbase - UN;
        if (nb + 1 < NB) {
#pragma unroll
            for (int k = 0; k < UN; ++k) nv[k] = pin[(nhbase + k) * HS];
        }
        // Current batch: running max descending in h, nontemporal stores.
#pragma unroll
        for (int k = UN - 1; k >= 0; --k) {
            m = fmax4(m, v[k]);
            store_nt(&pout[(hbase + k) * HS], m);
        }
#pragma unroll
        for (int k = 0; k < UN; ++k) v[k] = nv[k];
        hbase = nhbase;
    }
}

extern "C" void kernel_launch(void* const* d_in, const int* in_sizes, int n_in,
                              void* d_out, int out_size, void* d_ws, size_t ws_size,
                              hipStream_t stream) {
    const float4* in = (const float4*)d_in[0];
    float4* out = (float4*)d_out;
    const int nthreads = B * W * C4;  // 131072
    rev_cummax_kernel<<<nthreads / 256, 256, 0, stream>>>(in, out);
}